// Round 8
// baseline (224.695 us; speedup 1.0000x reference)
//
#include <hip/hip_runtime.h>
#include <hip/hip_fp16.h>
#include <math.h>

#define NPG 54
#define EPG 144
#define GLOB 10
#define VROW 216   // V row: 216 embeds only (g fused into out_mlp)
#define GPB 2      // graphs (waves) per block in graph_kernel

typedef _Float16 f16x8 __attribute__((ext_vector_type(8)));
typedef _Float16 f16x4 __attribute__((ext_vector_type(4)));
typedef float    f32x4 __attribute__((ext_vector_type(4)));

// intra-wave LDS fence: all this wave's DS ops complete + compiler ordering.
// (waves in a block share no LDS region -> no s_barrier needed anywhere)
#define WSYNC() asm volatile("s_waitcnt lgkmcnt(0)" ::: "memory")

// ---------------------------------------------------------------------------
// Kernel 1: one WAVE per graph, 2 graphs per 128-thread block, NO barriers.
// Adjacency built with native packed-fp16 LDS atomics (ds_pk_add_f16).
// LDS per graph = 10080 B. Blocks 0..127 additionally stage Wo1 -> fp16
// transposed/padded Wo1t[128][256] in workspace for the out-MLP kernel.
// ---------------------------------------------------------------------------
struct __align__(16) GL {
    _Float16 Adj[NPG][72];  // 7776 B
    _Float16 XH[16][72];    // 2304 B
};

__global__ __launch_bounds__(128, 4) void graph_kernel(
    const float* __restrict__ x,
    const int*   __restrict__ edge_index,
    const float* __restrict__ edge_attr,
    const float* __restrict__ W_rel1, const float* __restrict__ b1,
    const float* __restrict__ W_root1,
    const float* __restrict__ W_rel2, const float* __restrict__ b2,
    const float* __restrict__ W_root2,
    const float* __restrict__ Wo1,    // [226,128] fp32 (for prep)
    _Float16* __restrict__ wo1t,      // [128,256] fp16 out (prep)
    _Float16* __restrict__ v_out,     // [B, VROW] fp16
    int E_total)
{
    __shared__ GL S[GPB];
    const int tid  = threadIdx.x;
    const int w    = tid >> 6;
    const int lane = tid & 63;
    const int ln15 = lane & 15;
    const int quad = lane >> 4;
    const int g    = blockIdx.x * GPB + w;
    GL& L = S[w];
    const int nbase = g * NPG;
    const int ebase = g * EPG;

    _Float16 (*cat)[40] = (_Float16(*)[40])&L.Adj[0][0];       // overlay

    // ---- one-time Wo1 -> fp16 transposed staging (blocks 0..127) ----
    if (blockIdx.x < 128) {
        int n = blockIdx.x;
        int k = tid;                           // 0..127
        wo1t[n * 256 + k] = (_Float16)Wo1[(size_t)k * 128 + n];
        int k2 = tid + 128;                    // 128..255
        float v1 = (k2 < 226) ? Wo1[(size_t)k2 * 128 + n] : 0.0f;
        wo1t[n * 256 + k2] = (_Float16)v1;
    }

    // ---- issue global loads FIRST (stay in flight through zeroing) ----
    int   esrc_r[3], edst_r[3];
    float ea_r[3];
    #pragma unroll
    for (int k = 0; k < 3; k++) {
        int e = lane + 64 * k;
        if (e < EPG) {
            esrc_r[k] = edge_index[ebase + e] - nbase;
            edst_r[k] = edge_index[(size_t)E_total + ebase + e] - nbase;
            ea_r[k]   = edge_attr[ebase + e];
        } else { esrc_r[k] = 0; edst_r[k] = -1; ea_r[k] = 0.0f; }
    }
    f16x8 xv = {0, 0, 0, 0, 0, 0, 0, 0};
    if (lane < NPG) {
        const float4* xg4 = (const float4*)(x + (size_t)(nbase + lane) * 8);
        float4 lo = xg4[0], hi = xg4[1];
        xv = (f16x8){ (_Float16)lo.x, (_Float16)lo.y, (_Float16)lo.z, (_Float16)lo.w,
                      (_Float16)hi.x, (_Float16)hi.y, (_Float16)hi.z, (_Float16)hi.w };
    }

    // ---- weight B-fragments in registers ----
    f16x8 wf1 = {0, 0, 0, 0, 0, 0, 0, 0};
    if (quad == 0) {
        #pragma unroll
        for (int j = 0; j < 8; j++) wf1[j] = (_Float16)W_rel1[j * 16 + ln15];
    } else if (quad == 1) {
        #pragma unroll
        for (int j = 0; j < 8; j++) wf1[j] = (_Float16)W_root1[j * 16 + ln15];
    }
    f16x8 wf2 = {0, 0, 0, 0, 0, 0, 0, 0};
    if (ln15 < 4) {
        #pragma unroll
        for (int j = 0; j < 8; j++) {
            int k = quad * 8 + j;
            wf2[j] = (_Float16)((k < 16) ? W_rel2[k * 4 + ln15]
                                         : W_root2[(k - 16) * 4 + ln15]);
        }
    }
    const float b1v = b1[ln15];
    const float b2v = b2[ln15 & 3];

    // ---- zero the whole per-graph region (Adj54 + XH = 630 uint4) ----
    {
        uint4* z = (uint4*)&L;
        #pragma unroll
        for (int i = lane; i < 630; i += 64) z[i] = make_uint4(0, 0, 0, 0);
    }
    if (lane < NPG) {
        #pragma unroll
        for (int f = 0; f < 8; f++) L.XH[f][lane] = xv[f];
    }
    WSYNC();   // zeros + Xt in LDS before atomics land

    // ---- build Adj directly: one ds_pk_add_f16 per edge (dups sum in HW) ----
    #pragma unroll
    for (int k = 0; k < 3; k++) {
        if (edst_r[k] >= 0) {
            int s = esrc_r[k];
            __half2* cell = (__half2*)&L.Adj[edst_r[k]][s & ~1];
            __half a16 = __float2half(ea_r[k]);
            __half z16 = __float2half(0.0f);
            __half2 val = (s & 1) ? __halves2half2(z16, a16)
                                  : __halves2half2(a16, z16);
            unsafeAtomicAdd(cell, val);
        }
    }
    WSYNC();

    // ---- A-fragments (Adj) -> registers; rows 54..63 read finite garbage
    //      from the XH region (in-bounds), clamped downstream ----
    f16x8 af[4][2];
    #pragma unroll
    for (int t = 0; t < 4; t++)
        #pragma unroll
        for (int ks = 0; ks < 2; ks++)
            af[t][ks] = *(const f16x8*)&L.Adj[t * 16 + ln15][ks * 32 + quad * 8];
    WSYNC();   // af in regs before cat overlay writes

    // ---- cat overlay: x-root (cols 8..15) ----
    if (lane < NPG) *(f16x8*)&cat[lane][8] = xv;

    // ---- conv1: agg1 = Adj @ X ----
    f32x4 acc1[4];
    #pragma unroll
    for (int t = 0; t < 4; t++) acc1[t] = (f32x4){0.f, 0.f, 0.f, 0.f};
    #pragma unroll
    for (int ks = 0; ks < 2; ks++) {
        f16x8 bx = *(const f16x8*)&L.XH[ln15][ks * 32 + quad * 8];
        #pragma unroll
        for (int t = 0; t < 4; t++)
            acc1[t] = __builtin_amdgcn_mfma_f32_16x16x32_f16(af[t][ks], bx, acc1[t], 0, 0, 0);
    }
    #pragma unroll
    for (int t = 0; t < 4; t++)
        #pragma unroll
        for (int r = 0; r < 4; r++)
            if (ln15 < 8) cat[t * 16 + quad * 4 + r][ln15] = (_Float16)acc1[t][r];
    WSYNC();

    // ---- lin1: h1 = relu(b1 + [agg1|x] @ Wc1) ----
    f32x4 accL[4];
    #pragma unroll
    for (int t = 0; t < 4; t++) {
        f16x8 al = *(const f16x8*)&cat[t * 16 + ln15][quad * 8];
        f32x4 ci = (f32x4){b1v, b1v, b1v, b1v};
        accL[t] = __builtin_amdgcn_mfma_f32_16x16x32_f16(al, wf1, ci, 0, 0, 0);
    }
    #pragma unroll
    for (int t = 0; t < 4; t++) {
        f16x4 hp;
        #pragma unroll
        for (int r = 0; r < 4; r++) {
            int node = t * 16 + quad * 4 + r;
            float h = (node < NPG) ? fmaxf(accL[t][r], 0.0f) : 0.0f;
            hp[r] = (_Float16)h;
            cat[node][16 + ln15] = (_Float16)h;
        }
        *(f16x4*)&L.XH[ln15][t * 16 + quad * 4] = hp;
    }
    WSYNC();

    // ---- conv2: agg2 = Adj @ H1 (af from registers) ----
    f32x4 acc2[4];
    #pragma unroll
    for (int t = 0; t < 4; t++) acc2[t] = (f32x4){0.f, 0.f, 0.f, 0.f};
    #pragma unroll
    for (int ks = 0; ks < 2; ks++) {
        f16x8 bh = *(const f16x8*)&L.XH[ln15][ks * 32 + quad * 8];
        #pragma unroll
        for (int t = 0; t < 4; t++)
            acc2[t] = __builtin_amdgcn_mfma_f32_16x16x32_f16(af[t][ks], bh, acc2[t], 0, 0, 0);
    }
    #pragma unroll
    for (int t = 0; t < 4; t++)
        #pragma unroll
        for (int r = 0; r < 4; r++)
            cat[t * 16 + quad * 4 + r][ln15] = (_Float16)acc2[t][r];
    WSYNC();

    // ---- lin2: h2 = relu(b2 + [agg2|h1] @ Wc2); vtmp overlays XH ----
    _Float16* vt = &L.XH[0][0];
    #pragma unroll
    for (int t = 0; t < 4; t++) {
        f16x8 a2 = *(const f16x8*)&cat[t * 16 + ln15][quad * 8];
        f32x4 ci = (f32x4){b2v, b2v, b2v, b2v};
        f32x4 h2 = __builtin_amdgcn_mfma_f32_16x16x32_f16(a2, wf2, ci, 0, 0, 0);
        #pragma unroll
        for (int r = 0; r < 4; r++) {
            int node = t * 16 + quad * 4 + r;
            if (ln15 < 4 && node < NPG)
                vt[node * 4 + ln15] = (_Float16)fmaxf(h2[r], 0.0f);
        }
    }
    WSYNC();

    // ---- coalesced V write: cols 0..215 ----
    if (lane < 27)
        *(f16x8*)(v_out + (size_t)g * VROW + lane * 8) = *(const f16x8*)&vt[lane * 8];
}

// ---------------------------------------------------------------------------
// Kernel 2: out-MLP via fp16 MFMA, LDS-FREE. B-fragments load directly from
// pre-transposed Wo1t[128][256] fp16 in workspace (L2-resident, 64 KB).
// 256 threads (4 waves, 64 rows) x 512 blocks. gMLP fused per-lane in fp32.
// ---------------------------------------------------------------------------
__global__ __launch_bounds__(256) void out_mlp_mfma(
    const _Float16* __restrict__ V,     // [B, VROW] fp16
    const _Float16* __restrict__ Wo1t,  // [128, 256] fp16
    const float* __restrict__ gf,       // [B, 10]
    const float* __restrict__ Wg1, const float* __restrict__ bg1,
    const float* __restrict__ Wg2, const float* __restrict__ bg2,
    const float* __restrict__ Wg3, const float* __restrict__ bg3,
    const float* __restrict__ bo1,
    const float* __restrict__ Wo2,
    const float* __restrict__ bo2,
    float* __restrict__ out)
{
    const int tid  = threadIdx.x;
    const int w    = tid >> 6;
    const int ln15 = tid & 15;
    const int quad = (tid & 63) >> 4;
    const int rowbase = blockIdx.x * 64 + w * 16;
    const int row  = rowbase + ln15;

    float bo1v[8], wo2v[8];
    #pragma unroll
    for (int t = 0; t < 8; t++) {
        bo1v[t] = bo1[t * 16 + ln15];
        wo2v[t] = Wo2[t * 16 + ln15];
    }
    const float bo2v = bo2[0];

    // ---- per-lane global-MLP for this lane's row (fp32) ----
    float t3[GLOB];
    {
        const float* gr = gf + (size_t)row * GLOB;
        float t0[GLOB];
        #pragma unroll
        for (int i = 0; i < GLOB; i++) t0[i] = gr[i];
        float t1[8];
        #pragma unroll
        for (int j = 0; j < 8; j++) {
            float a = bg1[j];
            #pragma unroll
            for (int i = 0; i < GLOB; i++) a += t0[i] * Wg1[i * 8 + j];
            t1[j] = fmaxf(a, 0.0f);
        }
        float t2[8];
        #pragma unroll
        for (int j = 0; j < 8; j++) {
            float a = bg2[j];
            #pragma unroll
            for (int i = 0; i < 8; i++) a += t1[i] * Wg2[i * 8 + j];
            t2[j] = fmaxf(a, 0.0f);
        }
        #pragma unroll
        for (int j = 0; j < GLOB; j++) {
            float a = bg3[j];
            #pragma unroll
            for (int i = 0; i < 8; i++) a += t2[i] * Wg3[i * GLOB + j];
            t3[j] = fmaxf(a, 0.0f);
        }
    }

    // ---- A-fragments: s<6 from V; s=6 quad3 + s=7 quad0 from g ----
    const _Float16* Arow = V + (size_t)row * VROW;
    f16x8 af[8];
    #pragma unroll
    for (int s = 0; s < 6; s++)
        af[s] = *(const f16x8*)(Arow + s * 32 + quad * 8);
    if (quad == 3)
        af[6] = (f16x8){ (_Float16)t3[0], (_Float16)t3[1], (_Float16)t3[2], (_Float16)t3[3],
                         (_Float16)t3[4], (_Float16)t3[5], (_Float16)t3[6], (_Float16)t3[7] };
    else
        af[6] = *(const f16x8*)(Arow + 192 + quad * 8);
    af[7] = (f16x8){0, 0, 0, 0, 0, 0, 0, 0};
    if (quad == 0) { af[7][0] = (_Float16)t3[8]; af[7][1] = (_Float16)t3[9]; }

    // ---- main loop: B-fragments straight from global (L2-hit) ----
    f32x4 acc[8];
    #pragma unroll
    for (int t = 0; t < 8; t++) acc[t] = (f32x4){0.f, 0.f, 0.f, 0.f};

    #pragma unroll
    for (int s = 0; s < 8; s++) {
        f16x8 bf[8];
        #pragma unroll
        for (int t = 0; t < 8; t++)
            bf[t] = *(const f16x8*)(Wo1t + ((t * 16 + ln15) << 8) + s * 32 + quad * 8);
        #pragma unroll
        for (int t = 0; t < 8; t++)
            acc[t] = __builtin_amdgcn_mfma_f32_16x16x32_f16(af[s], bf[t], acc[t], 0, 0, 0);
    }

    // ---- epilogue: bias+relu+Wo2 dot (quad butterfly) + sigmoid ----
    #pragma unroll
    for (int rr = 0; rr < 4; rr++) {
        float p = 0.0f;
        #pragma unroll
        for (int t = 0; t < 8; t++) {
            float h = fmaxf(acc[t][rr] + bo1v[t], 0.0f);
            p += h * wo2v[t];
        }
        p += __shfl_xor(p, 1);
        p += __shfl_xor(p, 2);
        p += __shfl_xor(p, 4);
        p += __shfl_xor(p, 8);
        if (ln15 == rr) {
            int orow = rowbase + quad * 4 + rr;
            out[orow] = 1.0f / (1.0f + expf(-(p + bo2v)));
        }
    }
}

// ---------------------------------------------------------------------------
extern "C" void kernel_launch(void* const* d_in, const int* in_sizes, int n_in,
                              void* d_out, int out_size, void* d_ws, size_t ws_size,
                              hipStream_t stream) {
    const float* x        = (const float*)d_in[0];
    const int*   ei       = (const int*)  d_in[1];
    const float* ea       = (const float*)d_in[2];
    const float* gf       = (const float*)d_in[3];
    const float* W_rel1   = (const float*)d_in[4];
    const float* b1       = (const float*)d_in[5];
    const float* W_root1  = (const float*)d_in[6];
    const float* W_rel2   = (const float*)d_in[7];
    const float* b2       = (const float*)d_in[8];
    const float* W_root2  = (const float*)d_in[9];
    const float* Wg1      = (const float*)d_in[10];
    const float* bg1      = (const float*)d_in[11];
    const float* Wg2      = (const float*)d_in[12];
    const float* bg2      = (const float*)d_in[13];
    const float* Wg3      = (const float*)d_in[14];
    const float* bg3      = (const float*)d_in[15];
    const float* Wo1      = (const float*)d_in[16];
    const float* bo1      = (const float*)d_in[17];
    const float* Wo2      = (const float*)d_in[18];
    const float* bo2      = (const float*)d_in[19];

    float* out   = (float*)d_out;

    const int B = out_size;                     // 32768
    const int E = in_sizes[1] / 2;

    _Float16* V    = (_Float16*)d_ws;                           // [B,216]
    _Float16* Wo1t = (_Float16*)((char*)d_ws + (size_t)B * VROW * 2);  // [128,256]

    graph_kernel<<<B / GPB, 128, 0, stream>>>(
        x, ei, ea,
        W_rel1, b1, W_root1, W_rel2, b2, W_root2,
        Wo1, Wo1t, V, E);

    out_mlp_mfma<<<B / 64, 256, 0, stream>>>(
        V, Wo1t, gf, Wg1, bg1, Wg2, bg2, Wg3, bg3, bo1, Wo2, bo2, out);
}

// Round 9
// 213.239 us; speedup vs baseline: 1.0537x; 1.0537x over previous
//
#include <hip/hip_runtime.h>
#include <hip/hip_fp16.h>
#include <math.h>

#define NPG 54
#define EPG 144
#define GLOB 10
#define VROW 216   // V row: 216 embeds only (g fused into out_mlp)
#define GPB 2      // graphs (waves) per block in graph_kernel

typedef _Float16 f16x8 __attribute__((ext_vector_type(8)));
typedef _Float16 f16x4 __attribute__((ext_vector_type(4)));
typedef float    f32x4 __attribute__((ext_vector_type(4)));

// intra-wave LDS fence: all this wave's DS ops complete + compiler ordering.
// (waves in a block share no LDS region -> no s_barrier needed anywhere)
#define WSYNC() asm volatile("s_waitcnt lgkmcnt(0)" ::: "memory")

// ---------------------------------------------------------------------------
// Kernel 1: one WAVE per graph, 2 graphs per 128-thread block, NO barriers.
// Adjacency built with native packed-fp16 LDS atomics (ds_pk_add_f16).
// Adj row stride 56 (not 72): A-fragment k=54..63 reads spill into
// neighboring data (finite garbage), but every B operand (Xt/H1t) is zero
// for node-cols >= 54, so those products vanish -- bit-identical result.
// LDS per graph = 8352 B -> 16704 B/block -> 9 blocks/CU = 18 waves.
// ---------------------------------------------------------------------------
struct __align__(16) GL {
    _Float16 Adj[NPG][56];  // 6048 B (cols 54..55 zeroed, never written)
    _Float16 XH[16][72];    // 2304 B: Xt -> H1t -> vtmp (phase-disjoint)
};

__global__ __launch_bounds__(128, 5) void graph_kernel(
    const float* __restrict__ x,
    const int*   __restrict__ edge_index,
    const float* __restrict__ edge_attr,
    const float* __restrict__ W_rel1, const float* __restrict__ b1,
    const float* __restrict__ W_root1,
    const float* __restrict__ W_rel2, const float* __restrict__ b2,
    const float* __restrict__ W_root2,
    _Float16* __restrict__ v_out,     // [B, VROW] fp16
    int E_total)
{
    __shared__ GL S[GPB];
    const int tid  = threadIdx.x;
    const int w    = tid >> 6;
    const int lane = tid & 63;
    const int ln15 = lane & 15;
    const int quad = lane >> 4;
    const int g    = blockIdx.x * GPB + w;
    GL& L = S[w];
    const int nbase = g * NPG;
    const int ebase = g * EPG;

    _Float16 (*cat)[40] = (_Float16(*)[40])&L.Adj[0][0];   // overlay (5120 B)

    // ---- issue global loads FIRST (stay in flight through zeroing) ----
    int   esrc_r[3], edst_r[3];
    float ea_r[3];
    #pragma unroll
    for (int k = 0; k < 3; k++) {
        int e = lane + 64 * k;
        if (e < EPG) {
            esrc_r[k] = edge_index[ebase + e] - nbase;
            edst_r[k] = edge_index[(size_t)E_total + ebase + e] - nbase;
            ea_r[k]   = edge_attr[ebase + e];
        } else { esrc_r[k] = 0; edst_r[k] = -1; ea_r[k] = 0.0f; }
    }
    f16x8 xv = {0, 0, 0, 0, 0, 0, 0, 0};
    if (lane < NPG) {
        const float4* xg4 = (const float4*)(x + (size_t)(nbase + lane) * 8);
        float4 lo = xg4[0], hi = xg4[1];
        xv = (f16x8){ (_Float16)lo.x, (_Float16)lo.y, (_Float16)lo.z, (_Float16)lo.w,
                      (_Float16)hi.x, (_Float16)hi.y, (_Float16)hi.z, (_Float16)hi.w };
    }

    // ---- weight B-fragments in registers ----
    f16x8 wf1 = {0, 0, 0, 0, 0, 0, 0, 0};
    if (quad == 0) {
        #pragma unroll
        for (int j = 0; j < 8; j++) wf1[j] = (_Float16)W_rel1[j * 16 + ln15];
    } else if (quad == 1) {
        #pragma unroll
        for (int j = 0; j < 8; j++) wf1[j] = (_Float16)W_root1[j * 16 + ln15];
    }
    f16x8 wf2 = {0, 0, 0, 0, 0, 0, 0, 0};
    if (ln15 < 4) {
        #pragma unroll
        for (int j = 0; j < 8; j++) {
            int k = quad * 8 + j;
            wf2[j] = (_Float16)((k < 16) ? W_rel2[k * 4 + ln15]
                                         : W_root2[(k - 16) * 4 + ln15]);
        }
    }
    const float b1v = b1[ln15];
    const float b2v = b2[ln15 & 3];

    // ---- zero the whole per-graph region (8352 B = 522 uint4) ----
    {
        uint4* z = (uint4*)&L;
        #pragma unroll
        for (int i = lane; i < 522; i += 64) z[i] = make_uint4(0, 0, 0, 0);
    }
    if (lane < NPG) {
        #pragma unroll
        for (int f = 0; f < 8; f++) L.XH[f][lane] = xv[f];
    }
    WSYNC();   // zeros + Xt in LDS before atomics land

    // ---- build Adj directly: one ds_pk_add_f16 per edge (dups sum in HW) ----
    #pragma unroll
    for (int k = 0; k < 3; k++) {
        if (edst_r[k] >= 0) {
            int s = esrc_r[k];
            __half2* cell = (__half2*)&L.Adj[edst_r[k]][s & ~1];
            __half a16 = __float2half(ea_r[k]);
            __half z16 = __float2half(0.0f);
            __half2 val = (s & 1) ? __halves2half2(z16, a16)
                                  : __halves2half2(a16, z16);
            unsafeAtomicAdd(cell, val);
        }
    }
    WSYNC();

    // ---- A-fragments (Adj) -> registers. Reads beyond row width / rows>=54
    //      hit finite zero-or-garbage multiplied by zero B columns. ----
    f16x8 af[4][2];
    #pragma unroll
    for (int t = 0; t < 4; t++)
        #pragma unroll
        for (int ks = 0; ks < 2; ks++)
            af[t][ks] = *(const f16x8*)&L.Adj[t * 16 + ln15][ks * 32 + quad * 8];
    WSYNC();   // af in regs before cat overlay writes

    // ---- cat overlay: x-root (cols 8..15) ----
    if (lane < NPG) *(f16x8*)&cat[lane][8] = xv;

    // ---- conv1: agg1 = Adj @ X ----
    f32x4 acc1[4];
    #pragma unroll
    for (int t = 0; t < 4; t++) acc1[t] = (f32x4){0.f, 0.f, 0.f, 0.f};
    #pragma unroll
    for (int ks = 0; ks < 2; ks++) {
        f16x8 bx = *(const f16x8*)&L.XH[ln15][ks * 32 + quad * 8];
        #pragma unroll
        for (int t = 0; t < 4; t++)
            acc1[t] = __builtin_amdgcn_mfma_f32_16x16x32_f16(af[t][ks], bx, acc1[t], 0, 0, 0);
    }
    #pragma unroll
    for (int t = 0; t < 4; t++)
        #pragma unroll
        for (int r = 0; r < 4; r++)
            if (ln15 < 8) cat[t * 16 + quad * 4 + r][ln15] = (_Float16)acc1[t][r];
    WSYNC();

    // ---- lin1: h1 = relu(b1 + [agg1|x] @ Wc1) ----
    f32x4 accL[4];
    #pragma unroll
    for (int t = 0; t < 4; t++) {
        f16x8 al = *(const f16x8*)&cat[t * 16 + ln15][quad * 8];
        f32x4 ci = (f32x4){b1v, b1v, b1v, b1v};
        accL[t] = __builtin_amdgcn_mfma_f32_16x16x32_f16(al, wf1, ci, 0, 0, 0);
    }
    #pragma unroll
    for (int t = 0; t < 4; t++) {
        f16x4 hp;
        #pragma unroll
        for (int r = 0; r < 4; r++) {
            int node = t * 16 + quad * 4 + r;
            float h = (node < NPG) ? fmaxf(accL[t][r], 0.0f) : 0.0f;
            hp[r] = (_Float16)h;
            cat[node][16 + ln15] = (_Float16)h;
        }
        *(f16x4*)&L.XH[ln15][t * 16 + quad * 4] = hp;
    }
    WSYNC();

    // ---- conv2: agg2 = Adj @ H1 (af from registers) ----
    f32x4 acc2[4];
    #pragma unroll
    for (int t = 0; t < 4; t++) acc2[t] = (f32x4){0.f, 0.f, 0.f, 0.f};
    #pragma unroll
    for (int ks = 0; ks < 2; ks++) {
        f16x8 bh = *(const f16x8*)&L.XH[ln15][ks * 32 + quad * 8];
        #pragma unroll
        for (int t = 0; t < 4; t++)
            acc2[t] = __builtin_amdgcn_mfma_f32_16x16x32_f16(af[t][ks], bh, acc2[t], 0, 0, 0);
    }
    #pragma unroll
    for (int t = 0; t < 4; t++)
        #pragma unroll
        for (int r = 0; r < 4; r++)
            cat[t * 16 + quad * 4 + r][ln15] = (_Float16)acc2[t][r];
    WSYNC();

    // ---- lin2: h2 = relu(b2 + [agg2|h1] @ Wc2); vtmp overlays XH ----
    _Float16* vt = &L.XH[0][0];
    #pragma unroll
    for (int t = 0; t < 4; t++) {
        f16x8 a2 = *(const f16x8*)&cat[t * 16 + ln15][quad * 8];
        f32x4 ci = (f32x4){b2v, b2v, b2v, b2v};
        f32x4 h2 = __builtin_amdgcn_mfma_f32_16x16x32_f16(a2, wf2, ci, 0, 0, 0);
        #pragma unroll
        for (int r = 0; r < 4; r++) {
            int node = t * 16 + quad * 4 + r;
            if (ln15 < 4 && node < NPG)
                vt[node * 4 + ln15] = (_Float16)fmaxf(h2[r], 0.0f);
        }
    }
    WSYNC();

    // ---- coalesced V write: cols 0..215 ----
    if (lane < 27)
        *(f16x8*)(v_out + (size_t)g * VROW + lane * 8) = *(const f16x8*)&vt[lane * 8];
}

// ---------------------------------------------------------------------------
// Kernel 2: out-MLP via fp16 MFMA (R7 version: LDS Bt staging, 512 threads),
// with the 10->8->8->10 global MLP fused per-lane in fp32.
// ---------------------------------------------------------------------------
#define BTS 264

__global__ __launch_bounds__(512) void out_mlp_mfma(
    const _Float16* __restrict__ V,    // [B, VROW] fp16
    const float* __restrict__ gf,      // [B, 10]
    const float* __restrict__ Wg1, const float* __restrict__ bg1,
    const float* __restrict__ Wg2, const float* __restrict__ bg2,
    const float* __restrict__ Wg3, const float* __restrict__ bg3,
    const float* __restrict__ Wo1,     // [226, 128] fp32
    const float* __restrict__ bo1,
    const float* __restrict__ Wo2,
    const float* __restrict__ bo2,
    float* __restrict__ out)
{
    extern __shared__ _Float16 Bt[];   // [128][BTS] = 67584 B

    const int tid  = threadIdx.x;
    const int w    = tid >> 6;
    const int lane = tid & 63;
    const int ln15 = lane & 15;
    const int quad = lane >> 4;
    const int row0 = blockIdx.x * 128;
    const int row  = row0 + w * 16 + ln15;

    float bo1v[8], wo2v[8];
    #pragma unroll
    for (int t = 0; t < 8; t++) {
        bo1v[t] = bo1[t * 16 + ln15];
        wo2v[t] = Wo2[t * 16 + ln15];
    }
    const float bo2v = bo2[0];

    // ---- per-lane global-MLP for this lane's row (fp32) ----
    float t3[GLOB];
    {
        const float* gr = gf + (size_t)row * GLOB;
        float t0[GLOB];
        #pragma unroll
        for (int i = 0; i < GLOB; i++) t0[i] = gr[i];
        float t1[8];
        #pragma unroll
        for (int j = 0; j < 8; j++) {
            float a = bg1[j];
            #pragma unroll
            for (int i = 0; i < GLOB; i++) a += t0[i] * Wg1[i * 8 + j];
            t1[j] = fmaxf(a, 0.0f);
        }
        float t2[8];
        #pragma unroll
        for (int j = 0; j < 8; j++) {
            float a = bg2[j];
            #pragma unroll
            for (int i = 0; i < 8; i++) a += t1[i] * Wg2[i * 8 + j];
            t2[j] = fmaxf(a, 0.0f);
        }
        #pragma unroll
        for (int j = 0; j < GLOB; j++) {
            float a = bg3[j];
            #pragma unroll
            for (int i = 0; i < 8; i++) a += t2[i] * Wg3[i * GLOB + j];
            t3[j] = fmaxf(a, 0.0f);
        }
    }

    // ---- A-fragments: s<6 from V; s=6 quad3 + s=7 quad0 from g ----
    const _Float16* Arow = V + (size_t)row * VROW;
    f16x8 af[8];
    #pragma unroll
    for (int s = 0; s < 6; s++)
        af[s] = *(const f16x8*)(Arow + s * 32 + quad * 8);
    if (quad == 3)
        af[6] = (f16x8){ (_Float16)t3[0], (_Float16)t3[1], (_Float16)t3[2], (_Float16)t3[3],
                         (_Float16)t3[4], (_Float16)t3[5], (_Float16)t3[6], (_Float16)t3[7] };
    else
        af[6] = *(const f16x8*)(Arow + 192 + quad * 8);
    af[7] = (f16x8){0, 0, 0, 0, 0, 0, 0, 0};
    if (quad == 0) { af[7][0] = (_Float16)t3[8]; af[7][1] = (_Float16)t3[9]; }

    // ---- zero Bt, then stage Wo1 transposed fp16 ----
    {
        int4* bz = (int4*)Bt;
        for (int i = tid; i < 4224; i += 512)
            bz[i] = make_int4(0, 0, 0, 0);
    }
    __syncthreads();
    for (int i = tid; i < 7232; i += 512) {
        int k  = i >> 5;
        int nq = (i & 31) * 4;
        float4 v = *(const float4*)(Wo1 + (size_t)k * 128 + nq);
        Bt[(nq + 0) * BTS + k] = (_Float16)v.x;
        Bt[(nq + 1) * BTS + k] = (_Float16)v.y;
        Bt[(nq + 2) * BTS + k] = (_Float16)v.z;
        Bt[(nq + 3) * BTS + k] = (_Float16)v.w;
    }
    __syncthreads();

    f32x4 acc[8];
    #pragma unroll
    for (int t = 0; t < 8; t++) acc[t] = (f32x4){0.f, 0.f, 0.f, 0.f};

    for (int s = 0; s < 8; s++) {
        #pragma unroll
        for (int t = 0; t < 8; t++) {
            f16x8 bf = *(const f16x8*)&Bt[(t * 16 + ln15) * BTS + s * 32 + quad * 8];
            acc[t] = __builtin_amdgcn_mfma_f32_16x16x32_f16(af[s], bf, acc[t], 0, 0, 0);
        }
    }

    #pragma unroll
    for (int rr = 0; rr < 4; rr++) {
        float p = 0.0f;
        #pragma unroll
        for (int t = 0; t < 8; t++) {
            float h = fmaxf(acc[t][rr] + bo1v[t], 0.0f);
            p += h * wo2v[t];
        }
        p += __shfl_xor(p, 1);
        p += __shfl_xor(p, 2);
        p += __shfl_xor(p, 4);
        p += __shfl_xor(p, 8);
        if (ln15 == rr) {
            int orow = row0 + w * 16 + quad * 4 + rr;
            out[orow] = 1.0f / (1.0f + expf(-(p + bo2v)));
        }
    }
}

// ---------------------------------------------------------------------------
extern "C" void kernel_launch(void* const* d_in, const int* in_sizes, int n_in,
                              void* d_out, int out_size, void* d_ws, size_t ws_size,
                              hipStream_t stream) {
    const float* x        = (const float*)d_in[0];
    const int*   ei       = (const int*)  d_in[1];
    const float* ea       = (const float*)d_in[2];
    const float* gf       = (const float*)d_in[3];
    const float* W_rel1   = (const float*)d_in[4];
    const float* b1       = (const float*)d_in[5];
    const float* W_root1  = (const float*)d_in[6];
    const float* W_rel2   = (const float*)d_in[7];
    const float* b2       = (const float*)d_in[8];
    const float* W_root2  = (const float*)d_in[9];
    const float* Wg1      = (const float*)d_in[10];
    const float* bg1      = (const float*)d_in[11];
    const float* Wg2      = (const float*)d_in[12];
    const float* bg2      = (const float*)d_in[13];
    const float* Wg3      = (const float*)d_in[14];
    const float* bg3      = (const float*)d_in[15];
    const float* Wo1      = (const float*)d_in[16];
    const float* bo1      = (const float*)d_in[17];
    const float* Wo2      = (const float*)d_in[18];
    const float* bo2      = (const float*)d_in[19];

    float* out   = (float*)d_out;
    _Float16* V  = (_Float16*)d_ws;             // [B, VROW] fp16

    const int B = out_size;                     // 32768
    const int E = in_sizes[1] / 2;

    graph_kernel<<<B / GPB, 128, 0, stream>>>(
        x, ei, ea,
        W_rel1, b1, W_root1, W_rel2, b2, W_root2,
        V, E);

    out_mlp_mfma<<<B / 128, 512, 128 * BTS * sizeof(_Float16), stream>>>(
        V, gf, Wg1, bg1, Wg2, bg2, Wg3, bg3, Wo1, bo1, Wo2, bo2, out);
}